// Round 2
// baseline (819.979 us; speedup 1.0000x reference)
//
#include <hip/hip_runtime.h>

#define NN 100000
#define NE 1600000
#define FF 128
#define NG 64
#define GN_EPS 1e-5f

// ---------------- init: deg=1 (self loop), counters=0 ----------------
__global__ void k_init(float* deg, int* indeg, int* fill) {
    int i = blockIdx.x * blockDim.x + threadIdx.x;
    if (i < NN) { deg[i] = 1.0f; indeg[i] = 0; fill[i] = 0; }
}

// ---------------- degree + in-degree histogram ----------------
__global__ void k_deg(const int* ei, const float* ew, float* deg, int* indeg) {
    int e = blockIdx.x * blockDim.x + threadIdx.x;
    if (e < NE) {
        int d = ei[NE + e];
        atomicAdd(&deg[d], ew[e]);
        atomicAdd(&indeg[d], 1);
    }
}

// ---------------- deg -> dis = rsqrt(deg) (deg >= 1 always) ----------------
__global__ void k_dis(float* deg) {
    int i = blockIdx.x * blockDim.x + threadIdx.x;
    if (i < NN) deg[i] = rsqrtf(deg[i]);
}

// ---------------- exclusive scan of indeg -> rowptr (3 kernels) ----------------
__global__ void k_scan1(const int* in, int* out, int* bsum) {
    __shared__ int sd[256];
    int t = threadIdx.x;
    int base = blockIdx.x * 1024;
    int idx = base + t * 4;
    int v0 = (idx + 0 < NN) ? in[idx + 0] : 0;
    int v1 = (idx + 1 < NN) ? in[idx + 1] : 0;
    int v2 = (idx + 2 < NN) ? in[idx + 2] : 0;
    int v3 = (idx + 3 < NN) ? in[idx + 3] : 0;
    sd[t] = v0 + v1 + v2 + v3;
    __syncthreads();
    for (int off = 1; off < 256; off <<= 1) {
        int a = sd[t];
        int b = (t >= off) ? sd[t - off] : 0;
        __syncthreads();
        sd[t] = a + b;
        __syncthreads();
    }
    int excl = (t == 0) ? 0 : sd[t - 1];
    if (idx + 0 < NN) out[idx + 0] = excl; excl += v0;
    if (idx + 1 < NN) out[idx + 1] = excl; excl += v1;
    if (idx + 2 < NN) out[idx + 2] = excl; excl += v2;
    if (idx + 3 < NN) out[idx + 3] = excl;
    if (t == 255) bsum[blockIdx.x] = sd[255];
}

__global__ void k_scan2(int* bsum, int nb) {
    if (blockIdx.x == 0 && threadIdx.x == 0) {
        int acc = 0;
        for (int i = 0; i < nb; i++) { int v = bsum[i]; bsum[i] = acc; acc += v; }
    }
}

__global__ void k_scan3(int* out, const int* bsum) {
    int i = blockIdx.x * blockDim.x + threadIdx.x;
    if (i < NN) out[i] += bsum[i >> 10];
}

// ---------------- bucket edges by dst: CSR (src + precomputed norm) ----------------
__global__ void k_scatter(const int* ei, const float* ew, const float* dis,
                          const int* rowptr, int* fill, int* ssrc, float* snorm) {
    int e = blockIdx.x * blockDim.x + threadIdx.x;
    if (e < NE) {
        int s = ei[e];
        int d = ei[NE + e];
        int pos = rowptr[d] + atomicAdd(&fill[d], 1);
        ssrc[pos] = s;
        snorm[pos] = dis[s] * ew[e] * dis[d];
    }
}

// ---------------- xw = inputs @ W  (fp32, 32 rows/block) ----------------
__global__ __launch_bounds__(256) void k_gemm(const float* __restrict__ A,
                                              const float* __restrict__ W,
                                              float* __restrict__ xw) {
    __shared__ float As[32][FF];
    int t = threadIdx.x;
    int row0 = blockIdx.x * 32;
    const float4* A4 = (const float4*)(A + (size_t)row0 * FF);
    float4* As4 = (float4*)&As[0][0];
    for (int i = t; i < 32 * 32; i += 256) As4[i] = A4[i];
    __syncthreads();
    int rg = t >> 5;          // 0..7 -> 4 rows each
    int cg = t & 31;          // 0..31 -> 4 cols each
    float4 acc0 = {0,0,0,0}, acc1 = {0,0,0,0}, acc2 = {0,0,0,0}, acc3 = {0,0,0,0};
    for (int k = 0; k < FF; k++) {
        float4 w = *(const float4*)&W[(size_t)k * FF + cg * 4];
        float a0 = As[rg * 4 + 0][k];
        float a1 = As[rg * 4 + 1][k];
        float a2 = As[rg * 4 + 2][k];
        float a3 = As[rg * 4 + 3][k];
        acc0.x += a0 * w.x; acc0.y += a0 * w.y; acc0.z += a0 * w.z; acc0.w += a0 * w.w;
        acc1.x += a1 * w.x; acc1.y += a1 * w.y; acc1.z += a1 * w.z; acc1.w += a1 * w.w;
        acc2.x += a2 * w.x; acc2.y += a2 * w.y; acc2.z += a2 * w.z; acc2.w += a2 * w.w;
        acc3.x += a3 * w.x; acc3.y += a3 * w.y; acc3.z += a3 * w.z; acc3.w += a3 * w.w;
    }
    *(float4*)&xw[(size_t)(row0 + rg * 4 + 0) * FF + cg * 4] = acc0;
    *(float4*)&xw[(size_t)(row0 + rg * 4 + 1) * FF + cg * 4] = acc1;
    *(float4*)&xw[(size_t)(row0 + rg * 4 + 2) * FF + cg * 4] = acc2;
    *(float4*)&xw[(size_t)(row0 + rg * 4 + 3) * FF + cg * 4] = acc3;
}

// ---------------- aggregate: one wave per node, 2 feats/lane ----------------
__global__ __launch_bounds__(256) void k_agg(const int* __restrict__ rowptr,
                                             const int* __restrict__ indeg,
                                             const int* __restrict__ ssrc,
                                             const float* __restrict__ snorm,
                                             const float* __restrict__ xw,
                                             const float* __restrict__ dis,
                                             const float* __restrict__ bias,
                                             float* __restrict__ h) {
    int wid = (blockIdx.x * blockDim.x + threadIdx.x) >> 6;
    int lane = threadIdx.x & 63;
    if (wid >= NN) return;
    int start = rowptr[wid];
    int cnt = indeg[wid];
    float d = dis[wid];
    float sw = d * d;
    float2 xself = ((const float2*)(xw + (size_t)wid * FF))[lane];
    float2 bb = ((const float2*)bias)[lane];
    float ax = bb.x + sw * xself.x;
    float ay = bb.y + sw * xself.y;
    for (int i = 0; i < cnt; i++) {
        int s = ssrc[start + i];
        float w = snorm[start + i];
        float2 v = ((const float2*)(xw + (size_t)s * FF))[lane];
        ax += w * v.x;
        ay += w * v.y;
    }
    float2 r; r.x = ax; r.y = ay;
    ((float2*)(h + (size_t)wid * FF))[lane] = r;
}

// ---------------- graph start offsets from sorted batch ----------------
__global__ void k_gstart(const int* batch, int* gstart) {
    int i = blockIdx.x * blockDim.x + threadIdx.x;
    if (i >= NN) return;
    int b = batch[i];
    int prev = (i == 0) ? -1 : batch[i - 1];
    for (int g = prev + 1; g <= b; g++) gstart[g] = i;
    if (i == NN - 1) { for (int g = b + 1; g <= NG; g++) gstart[g] = NN; }
}

// ---------------- per-graph sum and sum-of-squares (one pass) ----------------
__global__ __launch_bounds__(512) void k_gsums(const float* __restrict__ h,
                                               const int* __restrict__ gstart,
                                               float* __restrict__ sum1,
                                               float* __restrict__ sum2) {
    __shared__ float s1[512], s2[512];
    int g = blockIdx.x;
    int t = threadIdx.x;
    int f = t & 127, st = t >> 7;
    int a = gstart[g], b = gstart[g + 1];
    float x = 0.f, x2 = 0.f;
    for (int n = a + st; n < b; n += 4) {
        float v = h[(size_t)n * FF + f];
        x += v; x2 += v * v;
    }
    s1[t] = x; s2[t] = x2;
    __syncthreads();
    if (st == 0) {
        x  = s1[t] + s1[t + 128] + s1[t + 256] + s1[t + 384];
        x2 = s2[t] + s2[t + 128] + s2[t + 256] + s2[t + 384];
        sum1[g * FF + f] = x;
        sum2[g * FF + f] = x2;
    }
}

// ---------------- per (g,f): center c = mean*mean_scale, inv std ----------------
__global__ void k_gstats(const float* sum1, const float* sum2, const int* gstart,
                         const float* ms, float* cfac, float* istd) {
    int i = blockIdx.x * blockDim.x + threadIdx.x;
    if (i >= NG * FF) return;
    int g = i >> 7, f = i & 127;
    float cnt = (float)max(gstart[g + 1] - gstart[g], 1);
    float mean = sum1[i] / cnt;
    float c = mean * ms[f];
    float var = sum2[i] / cnt - 2.f * c * mean + c * c;  // E[(h-c)^2]
    var = fmaxf(var, 0.f);
    cfac[i] = c;
    istd[i] = rsqrtf(var + GN_EPS);
}

// ---------------- normalize + relu -> h_emb ----------------
__global__ __launch_bounds__(256) void k_final(const float* __restrict__ h,
                                               const int* __restrict__ batch,
                                               const float* __restrict__ cfac,
                                               const float* __restrict__ istd,
                                               const float* __restrict__ gw,
                                               const float* __restrict__ gb,
                                               float* __restrict__ out) {
    int i = blockIdx.x * blockDim.x + threadIdx.x;   // over N*F/4
    if (i >= NN * FF / 4) return;
    int n = i >> 5;           // F/4 = 32 quads per node
    int fq = (i & 31) * 4;
    int g = batch[n];
    float4 h4 = *(const float4*)&h[(size_t)n * FF + fq];
    float4 c4 = *(const float4*)&cfac[g * FF + fq];
    float4 s4 = *(const float4*)&istd[g * FF + fq];
    float4 w4 = *(const float4*)&gw[fq];
    float4 b4 = *(const float4*)&gb[fq];
    float4 y;
    y.x = fmaxf(w4.x * (h4.x - c4.x) * s4.x + b4.x, 0.f);
    y.y = fmaxf(w4.y * (h4.y - c4.y) * s4.y + b4.y, 0.f);
    y.z = fmaxf(w4.z * (h4.z - c4.z) * s4.z + b4.z, 0.f);
    y.w = fmaxf(w4.w * (h4.w - c4.w) * s4.w + b4.w, 0.f);
    *(float4*)&out[(size_t)n * FF + fq] = y;
}

// ---------------- per-graph feature max over h_emb (relu'd => >= 0) ----------------
__global__ __launch_bounds__(512) void k_gmax(const float* __restrict__ hemb,
                                              const int* __restrict__ gstart,
                                              float* __restrict__ flat) {
    __shared__ float sm[512];
    int g = blockIdx.x;
    int t = threadIdx.x;
    int f = t & 127, st = t >> 7;
    int a = gstart[g], b = gstart[g + 1];
    float m = 0.f;
    for (int n = a + st; n < b; n += 4)
        m = fmaxf(m, hemb[(size_t)n * FF + f]);
    sm[t] = m;
    __syncthreads();
    if (st == 0)
        flat[g * FF + f] = fmaxf(fmaxf(sm[t], sm[t + 128]),
                                 fmaxf(sm[t + 256], sm[t + 384]));
}

// ---------------- passthrough outputs: edge_index, edge_weight, batch ----------------
__global__ void k_copy(const int* ei, const float* ew, const int* batch, float* out) {
    int i = blockIdx.x * blockDim.x + threadIdx.x;
    const int total = 2 * NE + NE + NN;
    if (i >= total) return;
    if (i < 2 * NE)       out[i] = (float)ei[i];
    else if (i < 3 * NE)  out[i] = ew[i - 2 * NE];
    else                  out[i] = (float)batch[i - 3 * NE];
}

extern "C" void kernel_launch(void* const* d_in, const int* in_sizes, int n_in,
                              void* d_out, int out_size, void* d_ws, size_t ws_size,
                              hipStream_t stream) {
    const float* inputs = (const float*)d_in[0];
    const int*   ei     = (const int*)d_in[1];
    const int*   batch  = (const int*)d_in[2];
    const float* ew     = (const float*)d_in[3];
    const float* W      = (const float*)d_in[4];
    const float* bias   = (const float*)d_in[5];
    const float* gnw    = (const float*)d_in[6];
    const float* gnb    = (const float*)d_in[7];
    const float* ms     = (const float*)d_in[8];
    float* out = (float*)d_out;

    // workspace layout
    char* p = (char*)d_ws;
    float* xw    = (float*)p; p += (size_t)NN * FF * 4;
    float* h     = (float*)p; p += (size_t)NN * FF * 4;
    float* dis   = (float*)p; p += (size_t)NN * 4;
    float* snorm = (float*)p; p += (size_t)NE * 4;
    float* sum1  = (float*)p; p += (size_t)NG * FF * 4;
    float* sum2  = (float*)p; p += (size_t)NG * FF * 4;
    float* cfac  = (float*)p; p += (size_t)NG * FF * 4;
    float* istd  = (float*)p; p += (size_t)NG * FF * 4;
    int* indeg   = (int*)p;   p += (size_t)NN * 4;
    int* rowptr  = (int*)p;   p += (size_t)NN * 4;
    int* fill    = (int*)p;   p += (size_t)NN * 4;
    int* ssrc    = (int*)p;   p += (size_t)NE * 4;
    int* gstart  = (int*)p;   p += (size_t)(NG + 1) * 4;
    int* bsum    = (int*)p;   p += 256 * 4;

    const int TB = 256;
    int nblkN  = (NN + TB - 1) / TB;          // 391
    int nblkE  = (NE + TB - 1) / TB;          // 6250
    int nscan  = (NN + 1023) / 1024;          // 98

    // output section offsets
    float* out_hemb = out;
    float* out_flat = out + (size_t)NN * FF;
    float* out_tail = out_flat + (size_t)NG * FF;

    k_init<<<nblkN, TB, 0, stream>>>(dis, indeg, fill);
    k_deg<<<nblkE, TB, 0, stream>>>(ei, ew, dis, indeg);
    k_dis<<<nblkN, TB, 0, stream>>>(dis);
    k_scan1<<<nscan, 256, 0, stream>>>(indeg, rowptr, bsum);
    k_scan2<<<1, 64, 0, stream>>>(bsum, nscan);
    k_scan3<<<nblkN, TB, 0, stream>>>(rowptr, bsum);
    k_scatter<<<nblkE, TB, 0, stream>>>(ei, ew, dis, rowptr, fill, ssrc, snorm);
    k_gemm<<<NN / 32, 256, 0, stream>>>(inputs, W, xw);
    k_agg<<<NN / 4, 256, 0, stream>>>(rowptr, indeg, ssrc, snorm, xw, dis, bias, h);
    k_gstart<<<nblkN, TB, 0, stream>>>(batch, gstart);
    k_gsums<<<NG, 512, 0, stream>>>(h, gstart, sum1, sum2);
    k_gstats<<<(NG * FF + TB - 1) / TB, TB, 0, stream>>>(sum1, sum2, gstart, ms, cfac, istd);
    k_final<<<(NN * FF / 4 + TB - 1) / TB, TB, 0, stream>>>(h, batch, cfac, istd, gnw, gnb, out_hemb);
    k_gmax<<<NG, 512, 0, stream>>>(out_hemb, gstart, out_flat);
    k_copy<<<(2 * NE + NE + NN + TB - 1) / TB, TB, 0, stream>>>(ei, ew, batch, out_tail);
}

// Round 3
// 586.786 us; speedup vs baseline: 1.3974x; 1.3974x over previous
//
#include <hip/hip_runtime.h>

#define NN 100000
#define NE 1600000
#define FF 128
#define NG 64
#define GN_EPS 1e-5f

typedef unsigned int uint;

// ---- bf16 helpers (packed 2 x bf16 in a uint) ----
__device__ __forceinline__ float bflo(uint u) { return __uint_as_float(u << 16); }
__device__ __forceinline__ float bfhi(uint u) { return __uint_as_float(u & 0xffff0000u); }
__device__ __forceinline__ uint f2bf1(float a) {
    uint ua = __float_as_uint(a);
    return (ua + 0x7fffu + ((ua >> 16) & 1u)) >> 16;
}
__device__ __forceinline__ uint f2bf_pack(float a, float b) {
    return f2bf1(a) | (f2bf1(b) << 16);
}

// ---------------- init: deg=1 (self loop), counters=0, zero stats+flat ----------------
__global__ void k_init(float* deg, int* indeg, int* fill,
                       float* sum1, float* sum2, int* flat_i) {
    int i = blockIdx.x * blockDim.x + threadIdx.x;
    if (i < NN) { deg[i] = 1.0f; indeg[i] = 0; fill[i] = 0; }
    if (i < NG * FF) { sum1[i] = 0.f; sum2[i] = 0.f; flat_i[i] = 0; }
}

// ---------------- degree + in-degree histogram ----------------
__global__ void k_deg(const int* ei, const float* ew, float* deg, int* indeg) {
    int e = blockIdx.x * blockDim.x + threadIdx.x;
    if (e < NE) {
        int d = ei[NE + e];
        atomicAdd(&deg[d], ew[e]);
        atomicAdd(&indeg[d], 1);
    }
}

// ---------------- deg -> dis = rsqrt(deg) (deg >= 1 always) ----------------
__global__ void k_dis(float* deg) {
    int i = blockIdx.x * blockDim.x + threadIdx.x;
    if (i < NN) deg[i] = rsqrtf(deg[i]);
}

// ---------------- exclusive scan of indeg -> rowptr (3 kernels) ----------------
__global__ void k_scan1(const int* in, int* out, int* bsum) {
    __shared__ int sd[256];
    int t = threadIdx.x;
    int base = blockIdx.x * 1024;
    int idx = base + t * 4;
    int v0 = (idx + 0 < NN) ? in[idx + 0] : 0;
    int v1 = (idx + 1 < NN) ? in[idx + 1] : 0;
    int v2 = (idx + 2 < NN) ? in[idx + 2] : 0;
    int v3 = (idx + 3 < NN) ? in[idx + 3] : 0;
    sd[t] = v0 + v1 + v2 + v3;
    __syncthreads();
    for (int off = 1; off < 256; off <<= 1) {
        int a = sd[t];
        int b = (t >= off) ? sd[t - off] : 0;
        __syncthreads();
        sd[t] = a + b;
        __syncthreads();
    }
    int excl = (t == 0) ? 0 : sd[t - 1];
    if (idx + 0 < NN) out[idx + 0] = excl; excl += v0;
    if (idx + 1 < NN) out[idx + 1] = excl; excl += v1;
    if (idx + 2 < NN) out[idx + 2] = excl; excl += v2;
    if (idx + 3 < NN) out[idx + 3] = excl;
    if (t == 255) bsum[blockIdx.x] = sd[255];
}

__global__ void k_scan2(int* bsum, int nb) {
    if (blockIdx.x == 0 && threadIdx.x == 0) {
        int acc = 0;
        for (int i = 0; i < nb; i++) { int v = bsum[i]; bsum[i] = acc; acc += v; }
    }
}

__global__ void k_scan3(int* out, const int* bsum) {
    int i = blockIdx.x * blockDim.x + threadIdx.x;
    if (i < NN) out[i] += bsum[i >> 10];
}

// ---------------- bucket edges by dst: CSR (src + precomputed norm) ----------------
__global__ void k_scatter(const int* ei, const float* ew, const float* dis,
                          const int* rowptr, int* fill, int* ssrc, float* snorm) {
    int e = blockIdx.x * blockDim.x + threadIdx.x;
    if (e < NE) {
        int s = ei[e];
        int d = ei[NE + e];
        int pos = rowptr[d] + atomicAdd(&fill[d], 1);
        ssrc[pos] = s;
        snorm[pos] = dis[s] * ew[e] * dis[d];
    }
}

// ---------------- xw = inputs @ W  (fp32 math, bf16 output) ----------------
__global__ __launch_bounds__(256) void k_gemm(const float* __restrict__ A,
                                              const float* __restrict__ W,
                                              uint* __restrict__ xwh) {
    __shared__ float As[32][FF];
    int t = threadIdx.x;
    int row0 = blockIdx.x * 32;
    const float4* A4 = (const float4*)(A + (size_t)row0 * FF);
    float4* As4 = (float4*)&As[0][0];
    for (int i = t; i < 32 * 32; i += 256) As4[i] = A4[i];
    __syncthreads();
    int rg = t >> 5;          // 0..7 -> 4 rows each
    int cg = t & 31;          // 0..31 -> 4 cols each
    float4 acc0 = {0,0,0,0}, acc1 = {0,0,0,0}, acc2 = {0,0,0,0}, acc3 = {0,0,0,0};
    for (int k = 0; k < FF; k++) {
        float4 w = *(const float4*)&W[(size_t)k * FF + cg * 4];
        float a0 = As[rg * 4 + 0][k];
        float a1 = As[rg * 4 + 1][k];
        float a2 = As[rg * 4 + 2][k];
        float a3 = As[rg * 4 + 3][k];
        acc0.x += a0 * w.x; acc0.y += a0 * w.y; acc0.z += a0 * w.z; acc0.w += a0 * w.w;
        acc1.x += a1 * w.x; acc1.y += a1 * w.y; acc1.z += a1 * w.z; acc1.w += a1 * w.w;
        acc2.x += a2 * w.x; acc2.y += a2 * w.y; acc2.z += a2 * w.z; acc2.w += a2 * w.w;
        acc3.x += a3 * w.x; acc3.y += a3 * w.y; acc3.z += a3 * w.z; acc3.w += a3 * w.w;
    }
    uint2 o0 = { f2bf_pack(acc0.x, acc0.y), f2bf_pack(acc0.z, acc0.w) };
    uint2 o1 = { f2bf_pack(acc1.x, acc1.y), f2bf_pack(acc1.z, acc1.w) };
    uint2 o2 = { f2bf_pack(acc2.x, acc2.y), f2bf_pack(acc2.z, acc2.w) };
    uint2 o3 = { f2bf_pack(acc3.x, acc3.y), f2bf_pack(acc3.z, acc3.w) };
    *(uint2*)&xwh[(size_t)(row0 + rg * 4 + 0) * 64 + cg * 2] = o0;
    *(uint2*)&xwh[(size_t)(row0 + rg * 4 + 1) * 64 + cg * 2] = o1;
    *(uint2*)&xwh[(size_t)(row0 + rg * 4 + 2) * 64 + cg * 2] = o2;
    *(uint2*)&xwh[(size_t)(row0 + rg * 4 + 3) * 64 + cg * 2] = o3;
}

// ---------------- aggregate: one wave per node, 2 feats/lane, bf16 gather ----------------
__global__ __launch_bounds__(256) void k_agg(const int* __restrict__ rowptr,
                                             const int* __restrict__ indeg,
                                             const int* __restrict__ ssrc,
                                             const float* __restrict__ snorm,
                                             const uint* __restrict__ xwh,
                                             const float* __restrict__ dis,
                                             const float* __restrict__ bias,
                                             uint* __restrict__ h32) {
    int wid = (blockIdx.x * blockDim.x + threadIdx.x) >> 6;
    int lane = threadIdx.x & 63;
    if (wid >= NN) return;
    int start = rowptr[wid];
    int cnt = indeg[wid];
    float d = dis[wid];
    float sw = d * d;
    uint us = xwh[(size_t)wid * 64 + lane];
    float2 bb = ((const float2*)bias)[lane];
    float ax = bb.x + sw * bflo(us);
    float ay = bb.y + sw * bfhi(us);
    int i = 0;
    for (; i + 1 < cnt; i += 2) {
        int s0 = ssrc[start + i];
        int s1 = ssrc[start + i + 1];
        float w0 = snorm[start + i];
        float w1 = snorm[start + i + 1];
        uint u0 = xwh[(size_t)s0 * 64 + lane];
        uint u1 = xwh[(size_t)s1 * 64 + lane];
        ax += w0 * bflo(u0); ay += w0 * bfhi(u0);
        ax += w1 * bflo(u1); ay += w1 * bfhi(u1);
    }
    if (i < cnt) {
        int s0 = ssrc[start + i];
        float w0 = snorm[start + i];
        uint u0 = xwh[(size_t)s0 * 64 + lane];
        ax += w0 * bflo(u0); ay += w0 * bfhi(u0);
    }
    h32[(size_t)wid * 64 + lane] = f2bf_pack(ax, ay);
}

// ---------------- graph start offsets from sorted batch ----------------
__global__ void k_gstart(const int* batch, int* gstart) {
    int i = blockIdx.x * blockDim.x + threadIdx.x;
    if (i >= NN) return;
    int b = batch[i];
    int prev = (i == 0) ? -1 : batch[i - 1];
    for (int g = prev + 1; g <= b; g++) gstart[g] = i;
    if (i == NN - 1) { for (int g = b + 1; g <= NG; g++) gstart[g] = NN; }
}

// ---------------- per-graph sum/sumsq: (graph x 8 strips) blocks, atomic partials ----------------
__global__ __launch_bounds__(256) void k_gsums(const uint* __restrict__ h32,
                                               const int* __restrict__ gstart,
                                               float* __restrict__ sum1,
                                               float* __restrict__ sum2) {
    __shared__ float s1a[256], s1b[256], s2a[256], s2b[256];
    int g = blockIdx.x >> 3;
    int s = blockIdx.x & 7;
    int t = threadIdx.x;
    int f2 = t & 63;        // u32 (feature pair) index
    int half = t >> 6;      // 0..3
    int a = gstart[g], b = gstart[g + 1];
    float x0 = 0.f, x1 = 0.f, y0 = 0.f, y1 = 0.f;
    for (int n = a + s * 4 + half; n < b; n += 32) {
        uint u = h32[(size_t)n * 64 + f2];
        float v0 = bflo(u), v1 = bfhi(u);
        x0 += v0; x1 += v1; y0 += v0 * v0; y1 += v1 * v1;
    }
    s1a[t] = x0; s1b[t] = x1; s2a[t] = y0; s2b[t] = y1;
    __syncthreads();
    if (half == 0) {
        for (int j = 1; j < 4; j++) {
            x0 += s1a[t + j * 64]; x1 += s1b[t + j * 64];
            y0 += s2a[t + j * 64]; y1 += s2b[t + j * 64];
        }
        atomicAdd(&sum1[g * FF + f2 * 2 + 0], x0);
        atomicAdd(&sum1[g * FF + f2 * 2 + 1], x1);
        atomicAdd(&sum2[g * FF + f2 * 2 + 0], y0);
        atomicAdd(&sum2[g * FF + f2 * 2 + 1], y1);
    }
}

// ---------------- per (g,f): center c = mean*mean_scale, inv std ----------------
__global__ void k_gstats(const float* sum1, const float* sum2, const int* gstart,
                         const float* ms, float* cfac, float* istd) {
    int i = blockIdx.x * blockDim.x + threadIdx.x;
    if (i >= NG * FF) return;
    int g = i >> 7, f = i & 127;
    float cnt = (float)max(gstart[g + 1] - gstart[g], 1);
    float mean = sum1[i] / cnt;
    float c = mean * ms[f];
    float var = sum2[i] / cnt - 2.f * c * mean + c * c;  // E[(h-c)^2]
    var = fmaxf(var, 0.f);
    cfac[i] = c;
    istd[i] = rsqrtf(var + GN_EPS);
}

// ---------------- normalize + relu -> h_emb, fused per-graph max (atomicMax) ----------------
__global__ __launch_bounds__(256) void k_final(const uint* __restrict__ h32,
                                               const int* __restrict__ batch,
                                               const float* __restrict__ cfac,
                                               const float* __restrict__ istd,
                                               const float* __restrict__ gw,
                                               const float* __restrict__ gb,
                                               float* __restrict__ out,
                                               int* __restrict__ flat_i) {
    __shared__ float sm[8][FF];
    __shared__ int gg[8];
    int t = threadIdx.x;
    int n0 = blockIdx.x * 8;
    int rq = t >> 5;          // row within block (0..7)
    int q = t & 31;           // feature quad index
    int n = n0 + rq;
    if (t < 8) gg[t] = batch[n0 + t];
    int g = batch[n];
    int fq = q * 4;
    uint2 hu = *(const uint2*)&h32[(size_t)n * 64 + q * 2];
    float4 h4 = { bflo(hu.x), bfhi(hu.x), bflo(hu.y), bfhi(hu.y) };
    float4 c4 = *(const float4*)&cfac[g * FF + fq];
    float4 s4 = *(const float4*)&istd[g * FF + fq];
    float4 w4 = *(const float4*)&gw[fq];
    float4 b4 = *(const float4*)&gb[fq];
    float4 y;
    y.x = fmaxf(w4.x * (h4.x - c4.x) * s4.x + b4.x, 0.f);
    y.y = fmaxf(w4.y * (h4.y - c4.y) * s4.y + b4.y, 0.f);
    y.z = fmaxf(w4.z * (h4.z - c4.z) * s4.z + b4.z, 0.f);
    y.w = fmaxf(w4.w * (h4.w - c4.w) * s4.w + b4.w, 0.f);
    *(float4*)&out[(size_t)n * FF + fq] = y;
    *(float4*)&sm[rq][fq] = y;
    __syncthreads();
    if (t < FF) {
        int f = t;
        int gprev = gg[0];
        float m = 0.f;
        for (int r = 0; r < 8; r++) {
            int gr = gg[r];
            if (gr != gprev) {
                atomicMax(&flat_i[gprev * FF + f], __float_as_int(m));
                m = 0.f; gprev = gr;
            }
            m = fmaxf(m, sm[r][f]);
        }
        atomicMax(&flat_i[gprev * FF + f], __float_as_int(m));
    }
}

// ---------------- passthrough outputs (vectorized) ----------------
__global__ void k_copy(const int4* __restrict__ ei4, const float4* __restrict__ ew4,
                       const int4* __restrict__ b4, float* __restrict__ out_tail) {
    int i = blockIdx.x * blockDim.x + threadIdx.x;
    if (i < 2 * NE / 4) {
        int4 v = ei4[i];
        float4 o = { (float)v.x, (float)v.y, (float)v.z, (float)v.w };
        *(float4*)&out_tail[(size_t)i * 4] = o;
    } else if (i < 2 * NE / 4 + NE / 4) {
        int j = i - 2 * NE / 4;
        *(float4*)&out_tail[2 * NE + (size_t)j * 4] = ew4[j];
    } else if (i < 2 * NE / 4 + NE / 4 + NN / 4) {
        int j = i - (2 * NE / 4 + NE / 4);
        int4 v = b4[j];
        float4 o = { (float)v.x, (float)v.y, (float)v.z, (float)v.w };
        *(float4*)&out_tail[3 * NE + (size_t)j * 4] = o;
    }
}

extern "C" void kernel_launch(void* const* d_in, const int* in_sizes, int n_in,
                              void* d_out, int out_size, void* d_ws, size_t ws_size,
                              hipStream_t stream) {
    const float* inputs = (const float*)d_in[0];
    const int*   ei     = (const int*)d_in[1];
    const int*   batch  = (const int*)d_in[2];
    const float* ew     = (const float*)d_in[3];
    const float* W      = (const float*)d_in[4];
    const float* bias   = (const float*)d_in[5];
    const float* gnw    = (const float*)d_in[6];
    const float* gnb    = (const float*)d_in[7];
    const float* ms     = (const float*)d_in[8];
    float* out = (float*)d_out;

    // workspace layout
    char* p = (char*)d_ws;
    uint* xwh    = (uint*)p;  p += (size_t)NN * 64 * 4;   // bf16 xw
    uint* h32    = (uint*)p;  p += (size_t)NN * 64 * 4;   // bf16 h
    float* dis   = (float*)p; p += (size_t)NN * 4;
    float* snorm = (float*)p; p += (size_t)NE * 4;
    float* sum1  = (float*)p; p += (size_t)NG * FF * 4;
    float* sum2  = (float*)p; p += (size_t)NG * FF * 4;
    float* cfac  = (float*)p; p += (size_t)NG * FF * 4;
    float* istd  = (float*)p; p += (size_t)NG * FF * 4;
    int* indeg   = (int*)p;   p += (size_t)NN * 4;
    int* rowptr  = (int*)p;   p += (size_t)NN * 4;
    int* fill    = (int*)p;   p += (size_t)NN * 4;
    int* ssrc    = (int*)p;   p += (size_t)NE * 4;
    int* gstart  = (int*)p;   p += (size_t)(NG + 1) * 4;
    int* bsum    = (int*)p;   p += 256 * 4;

    const int TB = 256;
    int nblkN  = (NN + TB - 1) / TB;          // 391
    int nblkE  = (NE + TB - 1) / TB;          // 6250
    int nscan  = (NN + 1023) / 1024;          // 98

    // output section offsets
    float* out_hemb = out;
    float* out_flat = out + (size_t)NN * FF;
    float* out_tail = out_flat + (size_t)NG * FF;
    int*   flat_i   = (int*)out_flat;

    k_init<<<nblkN, TB, 0, stream>>>(dis, indeg, fill, sum1, sum2, flat_i);
    k_deg<<<nblkE, TB, 0, stream>>>(ei, ew, dis, indeg);
    k_dis<<<nblkN, TB, 0, stream>>>(dis);
    k_scan1<<<nscan, 256, 0, stream>>>(indeg, rowptr, bsum);
    k_scan2<<<1, 64, 0, stream>>>(bsum, nscan);
    k_scan3<<<nblkN, TB, 0, stream>>>(rowptr, bsum);
    k_scatter<<<nblkE, TB, 0, stream>>>(ei, ew, dis, rowptr, fill, ssrc, snorm);
    k_gemm<<<NN / 32, 256, 0, stream>>>(inputs, W, xwh);
    k_agg<<<NN / 4, 256, 0, stream>>>(rowptr, indeg, ssrc, snorm, xwh, dis, bias, h32);
    k_gstart<<<nblkN, TB, 0, stream>>>(batch, gstart);
    k_gsums<<<NG * 8, 256, 0, stream>>>(h32, gstart, sum1, sum2);
    k_gstats<<<(NG * FF + TB - 1) / TB, TB, 0, stream>>>(sum1, sum2, gstart, ms, cfac, istd);
    k_final<<<NN / 8, 256, 0, stream>>>(h32, batch, cfac, istd, gnw, gnb, out_hemb, flat_i);
    k_copy<<<(2 * NE / 4 + NE / 4 + NN / 4 + TB - 1) / TB, TB, 0, stream>>>(
        (const int4*)ei, (const float4*)ew, (const int4*)batch, out_tail);
}

// Round 4
// 444.357 us; speedup vs baseline: 1.8453x; 1.3205x over previous
//
#include <hip/hip_runtime.h>

#define NN 100000
#define NE 1600000
#define FF 128
#define NG 64
#define GN_EPS 1e-5f

typedef unsigned int uint;
typedef unsigned long long ull;

// ---- bf16 helpers (packed 2 x bf16 in a uint) ----
__device__ __forceinline__ float bflo(uint u) { return __uint_as_float(u << 16); }
__device__ __forceinline__ float bfhi(uint u) { return __uint_as_float(u & 0xffff0000u); }
__device__ __forceinline__ uint f2bf1(float a) {
    uint ua = __float_as_uint(a);
    return (ua + 0x7fffu + ((ua >> 16) & 1u)) >> 16;
}
__device__ __forceinline__ uint f2bf_pack(float a, float b) {
    return f2bf1(a) | (f2bf1(b) << 16);
}

// ---------------- init: packed deg/count = 0, zero stats+flat ----------------
__global__ void k_init(ull* pk, float* sum1, float* sum2, int* flat_i) {
    int i = blockIdx.x * blockDim.x + threadIdx.x;
    if (i < NN) pk[i] = 0ULL;
    if (i < NG * FF) { sum1[i] = 0.f; sum2[i] = 0.f; flat_i[i] = 0; }
}

// ---------------- single packed atomic: [count:16 | fx(ew):48], rank = old count ----------------
__global__ void k_deg(const int* ei, const float* ew, ull* pk, int* rank) {
    int e = blockIdx.x * blockDim.x + threadIdx.x;
    if (e < NE) {
        int d = ei[NE + e];
        ull fx = (ull)(ew[e] * 4294967296.0f);          // 2^32 fixed point, < 2^32
        ull old = atomicAdd(&pk[d], (1ULL << 48) | fx);
        rank[e] = (int)(old >> 48);
    }
}

// ---------------- unpack: dis = rsqrt(1 + sum_ew), indeg = count ----------------
__global__ void k_dis(const ull* pk, float* dis, int* indeg) {
    int i = blockIdx.x * blockDim.x + threadIdx.x;
    if (i < NN) {
        ull p = pk[i];
        float deg = 1.0f + (float)((double)(p & 0xFFFFFFFFFFFFULL) * (1.0 / 4294967296.0));
        dis[i] = rsqrtf(deg);
        indeg[i] = (int)(p >> 48);
    }
}

// ---------------- exclusive scan of indeg -> rowptr (3 kernels) ----------------
__global__ void k_scan1(const int* in, int* out, int* bsum) {
    __shared__ int sd[256];
    int t = threadIdx.x;
    int base = blockIdx.x * 1024;
    int idx = base + t * 4;
    int v0 = (idx + 0 < NN) ? in[idx + 0] : 0;
    int v1 = (idx + 1 < NN) ? in[idx + 1] : 0;
    int v2 = (idx + 2 < NN) ? in[idx + 2] : 0;
    int v3 = (idx + 3 < NN) ? in[idx + 3] : 0;
    sd[t] = v0 + v1 + v2 + v3;
    __syncthreads();
    for (int off = 1; off < 256; off <<= 1) {
        int a = sd[t];
        int b = (t >= off) ? sd[t - off] : 0;
        __syncthreads();
        sd[t] = a + b;
        __syncthreads();
    }
    int excl = (t == 0) ? 0 : sd[t - 1];
    if (idx + 0 < NN) out[idx + 0] = excl; excl += v0;
    if (idx + 1 < NN) out[idx + 1] = excl; excl += v1;
    if (idx + 2 < NN) out[idx + 2] = excl; excl += v2;
    if (idx + 3 < NN) out[idx + 3] = excl;
    if (t == 255) bsum[blockIdx.x] = sd[255];
}

__global__ void k_scan2(int* bsum, int nb) {
    if (blockIdx.x == 0 && threadIdx.x == 0) {
        int acc = 0;
        for (int i = 0; i < nb; i++) { int v = bsum[i]; bsum[i] = acc; acc += v; }
    }
}

__global__ void k_scan3(int* out, const int* bsum) {
    int i = blockIdx.x * blockDim.x + threadIdx.x;
    if (i < NN) out[i] += bsum[i >> 10];
}

// ---------------- place edges: NO atomics, one 8B scattered store ----------------
__global__ void k_scatter(const int* ei, const float* ew, const float* dis,
                          const int* rowptr, const int* rank, int2* epair) {
    int e = blockIdx.x * blockDim.x + threadIdx.x;
    if (e < NE) {
        int s = ei[e];
        int d = ei[NE + e];
        float norm = dis[s] * ew[e] * dis[d];
        int pos = rowptr[d] + rank[e];
        epair[pos] = make_int2(s, __float_as_int(norm));
    }
}

// ---------------- xw = inputs @ W  (fp32 math, bf16 output) ----------------
__global__ __launch_bounds__(256) void k_gemm(const float* __restrict__ A,
                                              const float* __restrict__ W,
                                              uint* __restrict__ xwh) {
    __shared__ float As[32][FF];
    int t = threadIdx.x;
    int row0 = blockIdx.x * 32;
    const float4* A4 = (const float4*)(A + (size_t)row0 * FF);
    float4* As4 = (float4*)&As[0][0];
    for (int i = t; i < 32 * 32; i += 256) As4[i] = A4[i];
    __syncthreads();
    int rg = t >> 5;          // 0..7 -> 4 rows each
    int cg = t & 31;          // 0..31 -> 4 cols each
    float4 acc0 = {0,0,0,0}, acc1 = {0,0,0,0}, acc2 = {0,0,0,0}, acc3 = {0,0,0,0};
    for (int k = 0; k < FF; k++) {
        float4 w = *(const float4*)&W[(size_t)k * FF + cg * 4];
        float a0 = As[rg * 4 + 0][k];
        float a1 = As[rg * 4 + 1][k];
        float a2 = As[rg * 4 + 2][k];
        float a3 = As[rg * 4 + 3][k];
        acc0.x += a0 * w.x; acc0.y += a0 * w.y; acc0.z += a0 * w.z; acc0.w += a0 * w.w;
        acc1.x += a1 * w.x; acc1.y += a1 * w.y; acc1.z += a1 * w.z; acc1.w += a1 * w.w;
        acc2.x += a2 * w.x; acc2.y += a2 * w.y; acc2.z += a2 * w.z; acc2.w += a2 * w.w;
        acc3.x += a3 * w.x; acc3.y += a3 * w.y; acc3.z += a3 * w.z; acc3.w += a3 * w.w;
    }
    uint2 o0 = { f2bf_pack(acc0.x, acc0.y), f2bf_pack(acc0.z, acc0.w) };
    uint2 o1 = { f2bf_pack(acc1.x, acc1.y), f2bf_pack(acc1.z, acc1.w) };
    uint2 o2 = { f2bf_pack(acc2.x, acc2.y), f2bf_pack(acc2.z, acc2.w) };
    uint2 o3 = { f2bf_pack(acc3.x, acc3.y), f2bf_pack(acc3.z, acc3.w) };
    *(uint2*)&xwh[(size_t)(row0 + rg * 4 + 0) * 64 + cg * 2] = o0;
    *(uint2*)&xwh[(size_t)(row0 + rg * 4 + 1) * 64 + cg * 2] = o1;
    *(uint2*)&xwh[(size_t)(row0 + rg * 4 + 2) * 64 + cg * 2] = o2;
    *(uint2*)&xwh[(size_t)(row0 + rg * 4 + 3) * 64 + cg * 2] = o3;
}

// ---------------- aggregate: one wave per node, 2 feats/lane, unroll 4 ----------------
__global__ __launch_bounds__(256) void k_agg(const int* __restrict__ rowptr,
                                             const int* __restrict__ indeg,
                                             const int2* __restrict__ epair,
                                             const uint* __restrict__ xwh,
                                             const float* __restrict__ dis,
                                             const float* __restrict__ bias,
                                             uint* __restrict__ h32) {
    int wid = (blockIdx.x * blockDim.x + threadIdx.x) >> 6;
    int lane = threadIdx.x & 63;
    if (wid >= NN) return;
    int start = rowptr[wid];
    int cnt = indeg[wid];
    float d = dis[wid];
    float sw = d * d;
    uint us = xwh[(size_t)wid * 64 + lane];
    float2 bb = ((const float2*)bias)[lane];
    float ax = bb.x + sw * bflo(us);
    float ay = bb.y + sw * bfhi(us);
    int i = 0;
    for (; i + 3 < cnt; i += 4) {
        int2 p0 = epair[start + i + 0];
        int2 p1 = epair[start + i + 1];
        int2 p2 = epair[start + i + 2];
        int2 p3 = epair[start + i + 3];
        uint u0 = xwh[(size_t)p0.x * 64 + lane];
        uint u1 = xwh[(size_t)p1.x * 64 + lane];
        uint u2 = xwh[(size_t)p2.x * 64 + lane];
        uint u3 = xwh[(size_t)p3.x * 64 + lane];
        float w0 = __int_as_float(p0.y), w1 = __int_as_float(p1.y);
        float w2 = __int_as_float(p2.y), w3 = __int_as_float(p3.y);
        ax += w0 * bflo(u0); ay += w0 * bfhi(u0);
        ax += w1 * bflo(u1); ay += w1 * bfhi(u1);
        ax += w2 * bflo(u2); ay += w2 * bfhi(u2);
        ax += w3 * bflo(u3); ay += w3 * bfhi(u3);
    }
    for (; i < cnt; i++) {
        int2 p0 = epair[start + i];
        uint u0 = xwh[(size_t)p0.x * 64 + lane];
        float w0 = __int_as_float(p0.y);
        ax += w0 * bflo(u0); ay += w0 * bfhi(u0);
    }
    h32[(size_t)wid * 64 + lane] = f2bf_pack(ax, ay);
}

// ---------------- graph start offsets from sorted batch ----------------
__global__ void k_gstart(const int* batch, int* gstart) {
    int i = blockIdx.x * blockDim.x + threadIdx.x;
    if (i >= NN) return;
    int b = batch[i];
    int prev = (i == 0) ? -1 : batch[i - 1];
    for (int g = prev + 1; g <= b; g++) gstart[g] = i;
    if (i == NN - 1) { for (int g = b + 1; g <= NG; g++) gstart[g] = NN; }
}

// ---------------- per-graph sum/sumsq: (graph x 8 strips) blocks, atomic partials ----------------
__global__ __launch_bounds__(256) void k_gsums(const uint* __restrict__ h32,
                                               const int* __restrict__ gstart,
                                               float* __restrict__ sum1,
                                               float* __restrict__ sum2) {
    __shared__ float s1a[256], s1b[256], s2a[256], s2b[256];
    int g = blockIdx.x >> 3;
    int s = blockIdx.x & 7;
    int t = threadIdx.x;
    int f2 = t & 63;        // u32 (feature pair) index
    int half = t >> 6;      // 0..3
    int a = gstart[g], b = gstart[g + 1];
    float x0 = 0.f, x1 = 0.f, y0 = 0.f, y1 = 0.f;
    for (int n = a + s * 4 + half; n < b; n += 32) {
        uint u = h32[(size_t)n * 64 + f2];
        float v0 = bflo(u), v1 = bfhi(u);
        x0 += v0; x1 += v1; y0 += v0 * v0; y1 += v1 * v1;
    }
    s1a[t] = x0; s1b[t] = x1; s2a[t] = y0; s2b[t] = y1;
    __syncthreads();
    if (half == 0) {
        for (int j = 1; j < 4; j++) {
            x0 += s1a[t + j * 64]; x1 += s1b[t + j * 64];
            y0 += s2a[t + j * 64]; y1 += s2b[t + j * 64];
        }
        atomicAdd(&sum1[g * FF + f2 * 2 + 0], x0);
        atomicAdd(&sum1[g * FF + f2 * 2 + 1], x1);
        atomicAdd(&sum2[g * FF + f2 * 2 + 0], y0);
        atomicAdd(&sum2[g * FF + f2 * 2 + 1], y1);
    }
}

// ---------------- per (g,f): center c = mean*mean_scale, inv std ----------------
__global__ void k_gstats(const float* sum1, const float* sum2, const int* gstart,
                         const float* ms, float* cfac, float* istd) {
    int i = blockIdx.x * blockDim.x + threadIdx.x;
    if (i >= NG * FF) return;
    int g = i >> 7, f = i & 127;
    float cnt = (float)max(gstart[g + 1] - gstart[g], 1);
    float mean = sum1[i] / cnt;
    float c = mean * ms[f];
    float var = sum2[i] / cnt - 2.f * c * mean + c * c;  // E[(h-c)^2]
    var = fmaxf(var, 0.f);
    cfac[i] = c;
    istd[i] = rsqrtf(var + GN_EPS);
}

// ---------------- normalize + relu -> h_emb, fused per-graph max (atomicMax) ----------------
__global__ __launch_bounds__(256) void k_final(const uint* __restrict__ h32,
                                               const int* __restrict__ batch,
                                               const float* __restrict__ cfac,
                                               const float* __restrict__ istd,
                                               const float* __restrict__ gw,
                                               const float* __restrict__ gb,
                                               float* __restrict__ out,
                                               int* __restrict__ flat_i) {
    __shared__ float sm[8][FF];
    __shared__ int gg[8];
    int t = threadIdx.x;
    int n0 = blockIdx.x * 8;
    int rq = t >> 5;          // row within block (0..7)
    int q = t & 31;           // feature quad index
    int n = n0 + rq;
    if (t < 8) gg[t] = batch[n0 + t];
    int g = batch[n];
    int fq = q * 4;
    uint2 hu = *(const uint2*)&h32[(size_t)n * 64 + q * 2];
    float4 h4 = { bflo(hu.x), bfhi(hu.x), bflo(hu.y), bfhi(hu.y) };
    float4 c4 = *(const float4*)&cfac[g * FF + fq];
    float4 s4 = *(const float4*)&istd[g * FF + fq];
    float4 w4 = *(const float4*)&gw[fq];
    float4 b4 = *(const float4*)&gb[fq];
    float4 y;
    y.x = fmaxf(w4.x * (h4.x - c4.x) * s4.x + b4.x, 0.f);
    y.y = fmaxf(w4.y * (h4.y - c4.y) * s4.y + b4.y, 0.f);
    y.z = fmaxf(w4.z * (h4.z - c4.z) * s4.z + b4.z, 0.f);
    y.w = fmaxf(w4.w * (h4.w - c4.w) * s4.w + b4.w, 0.f);
    *(float4*)&out[(size_t)n * FF + fq] = y;
    *(float4*)&sm[rq][fq] = y;
    __syncthreads();
    if (t < FF) {
        int f = t;
        int gprev = gg[0];
        float m = 0.f;
        for (int r = 0; r < 8; r++) {
            int gr = gg[r];
            if (gr != gprev) {
                atomicMax(&flat_i[gprev * FF + f], __float_as_int(m));
                m = 0.f; gprev = gr;
            }
            m = fmaxf(m, sm[r][f]);
        }
        atomicMax(&flat_i[gprev * FF + f], __float_as_int(m));
    }
}

// ---------------- passthrough outputs (vectorized) ----------------
__global__ void k_copy(const int4* __restrict__ ei4, const float4* __restrict__ ew4,
                       const int4* __restrict__ b4, float* __restrict__ out_tail) {
    int i = blockIdx.x * blockDim.x + threadIdx.x;
    if (i < 2 * NE / 4) {
        int4 v = ei4[i];
        float4 o = { (float)v.x, (float)v.y, (float)v.z, (float)v.w };
        *(float4*)&out_tail[(size_t)i * 4] = o;
    } else if (i < 2 * NE / 4 + NE / 4) {
        int j = i - 2 * NE / 4;
        *(float4*)&out_tail[2 * NE + (size_t)j * 4] = ew4[j];
    } else if (i < 2 * NE / 4 + NE / 4 + NN / 4) {
        int j = i - (2 * NE / 4 + NE / 4);
        int4 v = b4[j];
        float4 o = { (float)v.x, (float)v.y, (float)v.z, (float)v.w };
        *(float4*)&out_tail[3 * NE + (size_t)j * 4] = o;
    }
}

extern "C" void kernel_launch(void* const* d_in, const int* in_sizes, int n_in,
                              void* d_out, int out_size, void* d_ws, size_t ws_size,
                              hipStream_t stream) {
    const float* inputs = (const float*)d_in[0];
    const int*   ei     = (const int*)d_in[1];
    const int*   batch  = (const int*)d_in[2];
    const float* ew     = (const float*)d_in[3];
    const float* W      = (const float*)d_in[4];
    const float* bias   = (const float*)d_in[5];
    const float* gnw    = (const float*)d_in[6];
    const float* gnb    = (const float*)d_in[7];
    const float* ms     = (const float*)d_in[8];
    float* out = (float*)d_out;

    // workspace layout
    char* p = (char*)d_ws;
    uint* xwh    = (uint*)p;  p += (size_t)NN * 64 * 4;   // bf16 xw
    uint* h32    = (uint*)p;  p += (size_t)NN * 64 * 4;   // bf16 h
    ull* pk      = (ull*)p;   p += (size_t)NN * 8;        // packed deg/count
    float* dis   = (float*)p; p += (size_t)NN * 4;
    float* sum1  = (float*)p; p += (size_t)NG * FF * 4;
    float* sum2  = (float*)p; p += (size_t)NG * FF * 4;
    float* cfac  = (float*)p; p += (size_t)NG * FF * 4;
    float* istd  = (float*)p; p += (size_t)NG * FF * 4;
    int* indeg   = (int*)p;   p += (size_t)NN * 4;
    int* rowptr  = (int*)p;   p += (size_t)NN * 4;
    int* rank    = (int*)p;   p += (size_t)NE * 4;
    int2* epair  = (int2*)p;  p += (size_t)NE * 8;
    int* gstart  = (int*)p;   p += (size_t)(NG + 1) * 4;
    int* bsum    = (int*)p;   p += 256 * 4;

    const int TB = 256;
    int nblkN  = (NN + TB - 1) / TB;          // 391
    int nblkE  = (NE + TB - 1) / TB;          // 6250
    int nscan  = (NN + 1023) / 1024;          // 98

    // output section offsets
    float* out_hemb = out;
    float* out_flat = out + (size_t)NN * FF;
    float* out_tail = out_flat + (size_t)NG * FF;
    int*   flat_i   = (int*)out_flat;

    k_init<<<nblkN, TB, 0, stream>>>(pk, sum1, sum2, flat_i);
    k_deg<<<nblkE, TB, 0, stream>>>(ei, ew, pk, rank);
    k_dis<<<nblkN, TB, 0, stream>>>(pk, dis, indeg);
    k_scan1<<<nscan, 256, 0, stream>>>(indeg, rowptr, bsum);
    k_scan2<<<1, 64, 0, stream>>>(bsum, nscan);
    k_scan3<<<nblkN, TB, 0, stream>>>(rowptr, bsum);
    k_scatter<<<nblkE, TB, 0, stream>>>(ei, ew, dis, rowptr, rank, epair);
    k_gemm<<<NN / 32, 256, 0, stream>>>(inputs, W, xwh);
    k_agg<<<NN / 4, 256, 0, stream>>>(rowptr, indeg, epair, xwh, dis, bias, h32);
    k_gstart<<<nblkN, TB, 0, stream>>>(batch, gstart);
    k_gsums<<<NG * 8, 256, 0, stream>>>(h32, gstart, sum1, sum2);
    k_gstats<<<(NG * FF + TB - 1) / TB, TB, 0, stream>>>(sum1, sum2, gstart, ms, cfac, istd);
    k_final<<<NN / 8, 256, 0, stream>>>(h32, batch, cfac, istd, gnw, gnb, out_hemb, flat_i);
    k_copy<<<(2 * NE / 4 + NE / 4 + NN / 4 + TB - 1) / TB, TB, 0, stream>>>(
        (const int4*)ei, (const float4*)ew, (const int4*)batch, out_tail);
}

// Round 5
// 393.621 us; speedup vs baseline: 2.0832x; 1.1289x over previous
//
#include <hip/hip_runtime.h>

#define NN 100000
#define NE 1600000
#define FF 128
#define NG 64
#define GN_EPS 1e-5f

typedef unsigned int uint;
typedef unsigned long long ull;
typedef unsigned short ushort;
typedef __attribute__((ext_vector_type(8))) short short8;
typedef __attribute__((ext_vector_type(4))) float f32x4;

// ---- bf16 helpers (packed 2 x bf16 in a uint) ----
__device__ __forceinline__ float bflo(uint u) { return __uint_as_float(u << 16); }
__device__ __forceinline__ float bfhi(uint u) { return __uint_as_float(u & 0xffff0000u); }
__device__ __forceinline__ uint f2bf1(float a) {
    uint ua = __float_as_uint(a);
    return (ua + 0x7fffu + ((ua >> 16) & 1u)) >> 16;
}
__device__ __forceinline__ uint f2bf_pack(float a, float b) {
    return f2bf1(a) | (f2bf1(b) << 16);
}

// ---------------- init: packed deg/count = 0, zero stats+flat ----------------
__global__ void k_init(ull* pk, float* sum1, float* sum2, int* flat_i) {
    int i = blockIdx.x * blockDim.x + threadIdx.x;
    if (i < NN) pk[i] = 0ULL;
    if (i < NG * FF) { sum1[i] = 0.f; sum2[i] = 0.f; flat_i[i] = 0; }
}

// ---------------- single packed atomic: [count:16 | fx(ew):48], rank = old count ----------------
__global__ void k_deg(const int* ei, const float* ew, ull* pk, int* rank) {
    int e = blockIdx.x * blockDim.x + threadIdx.x;
    if (e < NE) {
        int d = ei[NE + e];
        ull fx = (ull)(ew[e] * 4294967296.0f);          // 2^32 fixed point, < 2^32
        ull old = atomicAdd(&pk[d], (1ULL << 48) | fx);
        rank[e] = (int)(old >> 48);
    }
}

// ---------------- unpack: dis = rsqrt(1 + sum_ew), indeg = count ----------------
__global__ void k_dis(const ull* pk, float* dis, int* indeg) {
    int i = blockIdx.x * blockDim.x + threadIdx.x;
    if (i < NN) {
        ull p = pk[i];
        float deg = 1.0f + (float)((double)(p & 0xFFFFFFFFFFFFULL) * (1.0 / 4294967296.0));
        dis[i] = rsqrtf(deg);
        indeg[i] = (int)(p >> 48);
    }
}

// ---------------- exclusive scan of indeg -> rowptr (3 kernels) ----------------
__global__ void k_scan1(const int* in, int* out, int* bsum) {
    __shared__ int sd[256];
    int t = threadIdx.x;
    int base = blockIdx.x * 1024;
    int idx = base + t * 4;
    int v0 = (idx + 0 < NN) ? in[idx + 0] : 0;
    int v1 = (idx + 1 < NN) ? in[idx + 1] : 0;
    int v2 = (idx + 2 < NN) ? in[idx + 2] : 0;
    int v3 = (idx + 3 < NN) ? in[idx + 3] : 0;
    sd[t] = v0 + v1 + v2 + v3;
    __syncthreads();
    for (int off = 1; off < 256; off <<= 1) {
        int a = sd[t];
        int b = (t >= off) ? sd[t - off] : 0;
        __syncthreads();
        sd[t] = a + b;
        __syncthreads();
    }
    int excl = (t == 0) ? 0 : sd[t - 1];
    if (idx + 0 < NN) out[idx + 0] = excl; excl += v0;
    if (idx + 1 < NN) out[idx + 1] = excl; excl += v1;
    if (idx + 2 < NN) out[idx + 2] = excl; excl += v2;
    if (idx + 3 < NN) out[idx + 3] = excl;
    if (t == 255) bsum[blockIdx.x] = sd[255];
}

__global__ void k_scan2(int* bsum, int nb) {
    if (blockIdx.x == 0 && threadIdx.x == 0) {
        int acc = 0;
        for (int i = 0; i < nb; i++) { int v = bsum[i]; bsum[i] = acc; acc += v; }
    }
}

__global__ void k_scan3(int* out, const int* bsum) {
    int i = blockIdx.x * blockDim.x + threadIdx.x;
    if (i < NN) out[i] += bsum[i >> 10];
}

// ---------------- place edges: NO atomics, one 8B scattered store ----------------
__global__ void k_scatter(const int* ei, const float* ew, const float* dis,
                          const int* rowptr, const int* rank, int2* epair) {
    int e = blockIdx.x * blockDim.x + threadIdx.x;
    if (e < NE) {
        int s = ei[e];
        int d = ei[NE + e];
        float norm = dis[s] * ew[e] * dis[d];
        int pos = rowptr[d] + rank[e];
        epair[pos] = make_int2(s, __float_as_int(norm));
    }
}

// ---------------- W fp32 -> fragment-major bf16 (32 tiles x 64 lanes x 8 elems) ----------------
// tile = nt*4 + kt; lane l; element b:  W[kt*32 + (l>>4)*8 + b][nt*16 + (l&15)]
__global__ void k_wcvt(const float* __restrict__ W, uint4* __restrict__ wb) {
    int t = blockIdx.x * blockDim.x + threadIdx.x;   // 0..2047
    if (t >= 2048) return;
    int tile = t >> 6, l = t & 63;
    int nt = tile >> 2, kt = tile & 3;
    int j = nt * 16 + (l & 15);
    int kb = kt * 32 + (l >> 4) * 8;
    uint u[4];
    #pragma unroll
    for (int p = 0; p < 4; p++) {
        float e0 = W[(size_t)(kb + 2 * p + 0) * FF + j];
        float e1 = W[(size_t)(kb + 2 * p + 1) * FF + j];
        u[p] = f2bf_pack(e0, e1);
    }
    wb[t] = make_uint4(u[0], u[1], u[2], u[3]);
}

// ---------------- xw = inputs @ W via MFMA bf16 (64 rows/block, 4 waves) ----------------
__global__ __launch_bounds__(256) void k_gemm(const float* __restrict__ A,
                                              const uint4* __restrict__ wb,
                                              uint* __restrict__ xwh) {
    __shared__ uint4 wlds[2048];                     // 32 KB fragment-major W
    int t = threadIdx.x;
    for (int i = t; i < 2048; i += 256) wlds[i] = wb[i];
    __syncthreads();

    int wave = t >> 6, lane = t & 63;
    int kg = lane >> 4;                              // k-group 0..3
    int row = blockIdx.x * 64 + wave * 16 + (lane & 15);
    int rowc = row < NN ? row : NN - 1;              // clamp for tail loads

    const float4* A4 = (const float4*)A;
    short8 afrag[4];
    #pragma unroll
    for (int kt = 0; kt < 4; kt++) {
        float4 pq0 = A4[(size_t)rowc * 32 + kt * 8 + kg * 2 + 0];
        float4 pq1 = A4[(size_t)rowc * 32 + kt * 8 + kg * 2 + 1];
        uint u0 = f2bf_pack(pq0.x, pq0.y);
        uint u1 = f2bf_pack(pq0.z, pq0.w);
        uint u2 = f2bf_pack(pq1.x, pq1.y);
        uint u3 = f2bf_pack(pq1.z, pq1.w);
        uint2 lohi0 = { u0, u1 }, lohi1 = { u2, u3 };
        short8 f;
        f[0] = (short)(u0 & 0xffff); f[1] = (short)(u0 >> 16);
        f[2] = (short)(u1 & 0xffff); f[3] = (short)(u1 >> 16);
        f[4] = (short)(u2 & 0xffff); f[5] = (short)(u2 >> 16);
        f[6] = (short)(u3 & 0xffff); f[7] = (short)(u3 >> 16);
        afrag[kt] = f;
    }

    f32x4 acc[8];
    #pragma unroll
    for (int nt = 0; nt < 8; nt++) acc[nt] = (f32x4){0.f, 0.f, 0.f, 0.f};

    #pragma unroll
    for (int nt = 0; nt < 8; nt++) {
        #pragma unroll
        for (int kt = 0; kt < 4; kt++) {
            short8 bfrag = *(const short8*)&wlds[(nt * 4 + kt) * 64 + lane];
            acc[nt] = __builtin_amdgcn_mfma_f32_16x16x32_bf16(afrag[kt], bfrag, acc[nt], 0, 0, 0);
        }
    }

    // C/D layout: col = lane&15, row = (lane>>4)*4 + r
    ushort* xs = (ushort*)xwh;
    int col0 = lane & 15;
    #pragma unroll
    for (int nt = 0; nt < 8; nt++) {
        #pragma unroll
        for (int r = 0; r < 4; r++) {
            int rout = blockIdx.x * 64 + wave * 16 + kg * 4 + r;
            if (rout < NN)
                xs[(size_t)rout * FF + nt * 16 + col0] = (ushort)f2bf1(acc[nt][r]);
        }
    }
}

// ---------------- aggregate: one wave per node, 2 feats/lane, unroll 4 ----------------
__global__ __launch_bounds__(256) void k_agg(const int* __restrict__ rowptr,
                                             const int* __restrict__ indeg,
                                             const int2* __restrict__ epair,
                                             const uint* __restrict__ xwh,
                                             const float* __restrict__ dis,
                                             const float* __restrict__ bias,
                                             uint* __restrict__ h32) {
    int wid = (blockIdx.x * blockDim.x + threadIdx.x) >> 6;
    int lane = threadIdx.x & 63;
    if (wid >= NN) return;
    int start = rowptr[wid];
    int cnt = indeg[wid];
    float d = dis[wid];
    float sw = d * d;
    uint us = xwh[(size_t)wid * 64 + lane];
    float2 bb = ((const float2*)bias)[lane];
    float ax = bb.x + sw * bflo(us);
    float ay = bb.y + sw * bfhi(us);
    int i = 0;
    for (; i + 3 < cnt; i += 4) {
        int2 p0 = epair[start + i + 0];
        int2 p1 = epair[start + i + 1];
        int2 p2 = epair[start + i + 2];
        int2 p3 = epair[start + i + 3];
        uint u0 = xwh[(size_t)p0.x * 64 + lane];
        uint u1 = xwh[(size_t)p1.x * 64 + lane];
        uint u2 = xwh[(size_t)p2.x * 64 + lane];
        uint u3 = xwh[(size_t)p3.x * 64 + lane];
        float w0 = __int_as_float(p0.y), w1 = __int_as_float(p1.y);
        float w2 = __int_as_float(p2.y), w3 = __int_as_float(p3.y);
        ax += w0 * bflo(u0); ay += w0 * bfhi(u0);
        ax += w1 * bflo(u1); ay += w1 * bfhi(u1);
        ax += w2 * bflo(u2); ay += w2 * bfhi(u2);
        ax += w3 * bflo(u3); ay += w3 * bfhi(u3);
    }
    for (; i < cnt; i++) {
        int2 p0 = epair[start + i];
        uint u0 = xwh[(size_t)p0.x * 64 + lane];
        float w0 = __int_as_float(p0.y);
        ax += w0 * bflo(u0); ay += w0 * bfhi(u0);
    }
    h32[(size_t)wid * 64 + lane] = f2bf_pack(ax, ay);
}

// ---------------- graph start offsets from sorted batch ----------------
__global__ void k_gstart(const int* batch, int* gstart) {
    int i = blockIdx.x * blockDim.x + threadIdx.x;
    if (i >= NN) return;
    int b = batch[i];
    int prev = (i == 0) ? -1 : batch[i - 1];
    for (int g = prev + 1; g <= b; g++) gstart[g] = i;
    if (i == NN - 1) { for (int g = b + 1; g <= NG; g++) gstart[g] = NN; }
}

// ---------------- per-graph sum/sumsq: (graph x 8 strips) blocks, atomic partials ----------------
__global__ __launch_bounds__(256) void k_gsums(const uint* __restrict__ h32,
                                               const int* __restrict__ gstart,
                                               float* __restrict__ sum1,
                                               float* __restrict__ sum2) {
    __shared__ float s1a[256], s1b[256], s2a[256], s2b[256];
    int g = blockIdx.x >> 3;
    int s = blockIdx.x & 7;
    int t = threadIdx.x;
    int f2 = t & 63;        // u32 (feature pair) index
    int half = t >> 6;      // 0..3
    int a = gstart[g], b = gstart[g + 1];
    float x0 = 0.f, x1 = 0.f, y0 = 0.f, y1 = 0.f;
    for (int n = a + s * 4 + half; n < b; n += 32) {
        uint u = h32[(size_t)n * 64 + f2];
        float v0 = bflo(u), v1 = bfhi(u);
        x0 += v0; x1 += v1; y0 += v0 * v0; y1 += v1 * v1;
    }
    s1a[t] = x0; s1b[t] = x1; s2a[t] = y0; s2b[t] = y1;
    __syncthreads();
    if (half == 0) {
        for (int j = 1; j < 4; j++) {
            x0 += s1a[t + j * 64]; x1 += s1b[t + j * 64];
            y0 += s2a[t + j * 64]; y1 += s2b[t + j * 64];
        }
        atomicAdd(&sum1[g * FF + f2 * 2 + 0], x0);
        atomicAdd(&sum1[g * FF + f2 * 2 + 1], x1);
        atomicAdd(&sum2[g * FF + f2 * 2 + 0], y0);
        atomicAdd(&sum2[g * FF + f2 * 2 + 1], y1);
    }
}

// ---------------- per (g,f): center c = mean*mean_scale, inv std ----------------
__global__ void k_gstats(const float* sum1, const float* sum2, const int* gstart,
                         const float* ms, float* cfac, float* istd) {
    int i = blockIdx.x * blockDim.x + threadIdx.x;
    if (i >= NG * FF) return;
    int g = i >> 7, f = i & 127;
    float cnt = (float)max(gstart[g + 1] - gstart[g], 1);
    float mean = sum1[i] / cnt;
    float c = mean * ms[f];
    float var = sum2[i] / cnt - 2.f * c * mean + c * c;  // E[(h-c)^2]
    var = fmaxf(var, 0.f);
    cfac[i] = c;
    istd[i] = rsqrtf(var + GN_EPS);
}

// ---------------- normalize + relu -> h_emb, fused per-graph max (atomicMax) ----------------
__global__ __launch_bounds__(256) void k_final(const uint* __restrict__ h32,
                                               const int* __restrict__ batch,
                                               const float* __restrict__ cfac,
                                               const float* __restrict__ istd,
                                               const float* __restrict__ gw,
                                               const float* __restrict__ gb,
                                               float* __restrict__ out,
                                               int* __restrict__ flat_i) {
    __shared__ float sm[8][FF];
    __shared__ int gg[8];
    int t = threadIdx.x;
    int n0 = blockIdx.x * 8;
    int rq = t >> 5;          // row within block (0..7)
    int q = t & 31;           // feature quad index
    int n = n0 + rq;
    if (t < 8) gg[t] = batch[n0 + t];
    int g = batch[n];
    int fq = q * 4;
    uint2 hu = *(const uint2*)&h32[(size_t)n * 64 + q * 2];
    float4 h4 = { bflo(hu.x), bfhi(hu.x), bflo(hu.y), bfhi(hu.y) };
    float4 c4 = *(const float4*)&cfac[g * FF + fq];
    float4 s4 = *(const float4*)&istd[g * FF + fq];
    float4 w4 = *(const float4*)&gw[fq];
    float4 b4 = *(const float4*)&gb[fq];
    float4 y;
    y.x = fmaxf(w4.x * (h4.x - c4.x) * s4.x + b4.x, 0.f);
    y.y = fmaxf(w4.y * (h4.y - c4.y) * s4.y + b4.y, 0.f);
    y.z = fmaxf(w4.z * (h4.z - c4.z) * s4.z + b4.z, 0.f);
    y.w = fmaxf(w4.w * (h4.w - c4.w) * s4.w + b4.w, 0.f);
    *(float4*)&out[(size_t)n * FF + fq] = y;
    *(float4*)&sm[rq][fq] = y;
    __syncthreads();
    if (t < FF) {
        int f = t;
        int gprev = gg[0];
        float m = 0.f;
        for (int r = 0; r < 8; r++) {
            int gr = gg[r];
            if (gr != gprev) {
                atomicMax(&flat_i[gprev * FF + f], __float_as_int(m));
                m = 0.f; gprev = gr;
            }
            m = fmaxf(m, sm[r][f]);
        }
        atomicMax(&flat_i[gprev * FF + f], __float_as_int(m));
    }
}

// ---------------- passthrough outputs (vectorized) ----------------
__global__ void k_copy(const int4* __restrict__ ei4, const float4* __restrict__ ew4,
                       const int4* __restrict__ b4, float* __restrict__ out_tail) {
    int i = blockIdx.x * blockDim.x + threadIdx.x;
    if (i < 2 * NE / 4) {
        int4 v = ei4[i];
        float4 o = { (float)v.x, (float)v.y, (float)v.z, (float)v.w };
        *(float4*)&out_tail[(size_t)i * 4] = o;
    } else if (i < 2 * NE / 4 + NE / 4) {
        int j = i - 2 * NE / 4;
        *(float4*)&out_tail[2 * NE + (size_t)j * 4] = ew4[j];
    } else if (i < 2 * NE / 4 + NE / 4 + NN / 4) {
        int j = i - (2 * NE / 4 + NE / 4);
        int4 v = b4[j];
        float4 o = { (float)v.x, (float)v.y, (float)v.z, (float)v.w };
        *(float4*)&out_tail[3 * NE + (size_t)j * 4] = o;
    }
}

extern "C" void kernel_launch(void* const* d_in, const int* in_sizes, int n_in,
                              void* d_out, int out_size, void* d_ws, size_t ws_size,
                              hipStream_t stream) {
    const float* inputs = (const float*)d_in[0];
    const int*   ei     = (const int*)d_in[1];
    const int*   batch  = (const int*)d_in[2];
    const float* ew     = (const float*)d_in[3];
    const float* W      = (const float*)d_in[4];
    const float* bias   = (const float*)d_in[5];
    const float* gnw    = (const float*)d_in[6];
    const float* gnb    = (const float*)d_in[7];
    const float* ms     = (const float*)d_in[8];
    float* out = (float*)d_out;

    // workspace layout
    char* p = (char*)d_ws;
    uint* xwh    = (uint*)p;  p += (size_t)NN * 64 * 4;   // bf16 xw
    uint* h32    = (uint*)p;  p += (size_t)NN * 64 * 4;   // bf16 h
    ull* pk      = (ull*)p;   p += (size_t)NN * 8;        // packed deg/count
    float* dis   = (float*)p; p += (size_t)NN * 4;
    float* sum1  = (float*)p; p += (size_t)NG * FF * 4;
    float* sum2  = (float*)p; p += (size_t)NG * FF * 4;
    float* cfac  = (float*)p; p += (size_t)NG * FF * 4;
    float* istd  = (float*)p; p += (size_t)NG * FF * 4;
    int* indeg   = (int*)p;   p += (size_t)NN * 4;
    int* rowptr  = (int*)p;   p += (size_t)NN * 4;
    int* rank    = (int*)p;   p += (size_t)NE * 4;
    int2* epair  = (int2*)p;  p += (size_t)NE * 8;
    int* gstart  = (int*)p;   p += (size_t)(NG + 1) * 4;
    int* bsum    = (int*)p;   p += 256 * 4;
    uint4* wb    = (uint4*)p; p += 2048 * 16;             // fragment-major bf16 W

    const int TB = 256;
    int nblkN  = (NN + TB - 1) / TB;          // 391
    int nblkE  = (NE + TB - 1) / TB;          // 6250
    int nscan  = (NN + 1023) / 1024;          // 98

    // output section offsets
    float* out_hemb = out;
    float* out_flat = out + (size_t)NN * FF;
    float* out_tail = out_flat + (size_t)NG * FF;
    int*   flat_i   = (int*)out_flat;

    k_init<<<nblkN, TB, 0, stream>>>(pk, sum1, sum2, flat_i);
    k_deg<<<nblkE, TB, 0, stream>>>(ei, ew, pk, rank);
    k_dis<<<nblkN, TB, 0, stream>>>(pk, dis, indeg);
    k_scan1<<<nscan, 256, 0, stream>>>(indeg, rowptr, bsum);
    k_scan2<<<1, 64, 0, stream>>>(bsum, nscan);
    k_scan3<<<nblkN, TB, 0, stream>>>(rowptr, bsum);
    k_scatter<<<nblkE, TB, 0, stream>>>(ei, ew, dis, rowptr, rank, epair);
    k_wcvt<<<8, 256, 0, stream>>>(W, wb);
    k_gemm<<<(NN + 63) / 64, 256, 0, stream>>>(inputs, wb, xwh);
    k_agg<<<NN / 4, 256, 0, stream>>>(rowptr, indeg, epair, xwh, dis, bias, h32);
    k_gstart<<<nblkN, TB, 0, stream>>>(batch, gstart);
    k_gsums<<<NG * 8, 256, 0, stream>>>(h32, gstart, sum1, sum2);
    k_gstats<<<(NG * FF + TB - 1) / TB, TB, 0, stream>>>(sum1, sum2, gstart, ms, cfac, istd);
    k_final<<<NN / 8, 256, 0, stream>>>(h32, batch, cfac, istd, gnw, gnb, out_hemb, flat_i);
    k_copy<<<(2 * NE / 4 + NE / 4 + NN / 4 + TB - 1) / TB, TB, 0, stream>>>(
        (const int4*)ei, (const float4*)ew, (const int4*)batch, out_tail);
}

// Round 6
// 385.302 us; speedup vs baseline: 2.1281x; 1.0216x over previous
//
#include <hip/hip_runtime.h>

#define NN 100000
#define NE 1600000
#define FF 128
#define NG 64
#define GN_EPS 1e-5f
#define SLOT 64

typedef unsigned int uint;
typedef unsigned long long ull;
typedef unsigned short ushort;
typedef __attribute__((ext_vector_type(8))) short short8;
typedef __attribute__((ext_vector_type(4))) float f32x4;

// ---- bf16 helpers (packed 2 x bf16 in a uint) ----
__device__ __forceinline__ float bflo(uint u) { return __uint_as_float(u << 16); }
__device__ __forceinline__ float bfhi(uint u) { return __uint_as_float(u & 0xffff0000u); }
__device__ __forceinline__ uint f2bf1(float a) {
    uint ua = __float_as_uint(a);
    return (ua + 0x7fffu + ((ua >> 16) & 1u)) >> 16;
}
__device__ __forceinline__ uint f2bf_pack(float a, float b) {
    return f2bf1(a) | (f2bf1(b) << 16);
}

// ---------------- init: packed deg/count = 0, zero stats+flat ----------------
__global__ void k_init(ull* pk, float* sum1, float* sum2, int* flat_i) {
    int i = blockIdx.x * blockDim.x + threadIdx.x;
    if (i < NN) pk[i] = 0ULL;
    if (i < NG * FF) { sum1[i] = 0.f; sum2[i] = 0.f; flat_i[i] = 0; }
}

// ---- one packed atomic per edge: [count:16 | fx(ew):48]; scatter (s,ew) to slot ----
__global__ void k_deg(const int* __restrict__ ei, const float* __restrict__ ew,
                      ull* __restrict__ pk, int2* __restrict__ eslot) {
    int e = blockIdx.x * blockDim.x + threadIdx.x;
    if (e < NE) {
        int s = ei[e];
        int d = ei[NE + e];
        float w = ew[e];
        ull fx = (ull)(w * 4294967296.0f);              // 2^32 fixed point
        ull old = atomicAdd(&pk[d], (1ULL << 48) | fx);
        int r = (int)(old >> 48);
        if (r < SLOT)
            eslot[(size_t)d * SLOT + r] = make_int2(s, __float_as_int(w));
    }
}

// ---- unpack: dis = rsqrt(1 + sum_ew), indeg = count; also graph starts ----
__global__ void k_dis(const ull* __restrict__ pk, float* __restrict__ dis,
                      int* __restrict__ indeg, const int* __restrict__ batch,
                      int* __restrict__ gstart) {
    int i = blockIdx.x * blockDim.x + threadIdx.x;
    if (i >= NN) return;
    ull p = pk[i];
    float deg = 1.0f + (float)((double)(p & 0xFFFFFFFFFFFFULL) * (1.0 / 4294967296.0));
    dis[i] = rsqrtf(deg);
    int c = (int)(p >> 48);
    indeg[i] = c < SLOT ? c : SLOT;
    int b = batch[i];
    int prev = (i == 0) ? -1 : batch[i - 1];
    for (int g = prev + 1; g <= b; g++) gstart[g] = i;
    if (i == NN - 1) { for (int g = b + 1; g <= NG; g++) gstart[g] = NN; }
}

// ---------------- W fp32 -> fragment-major bf16 (32 tiles x 64 lanes x 8 elems) ----------------
// tile = nt*4 + kt; lane l; element b:  W[kt*32 + (l>>4)*8 + b][nt*16 + (l&15)]
__global__ void k_wcvt(const float* __restrict__ W, uint4* __restrict__ wb) {
    int t = blockIdx.x * blockDim.x + threadIdx.x;   // 0..2047
    if (t >= 2048) return;
    int tile = t >> 6, l = t & 63;
    int nt = tile >> 2, kt = tile & 3;
    int j = nt * 16 + (l & 15);
    int kb = kt * 32 + (l >> 4) * 8;
    uint u[4];
    #pragma unroll
    for (int p = 0; p < 4; p++) {
        float e0 = W[(size_t)(kb + 2 * p + 0) * FF + j];
        float e1 = W[(size_t)(kb + 2 * p + 1) * FF + j];
        u[p] = f2bf_pack(e0, e1);
    }
    wb[t] = make_uint4(u[0], u[1], u[2], u[3]);
}

// ---- xws = dis[row] * (inputs @ W) via MFMA bf16 (64 rows/block, 4 waves) ----
__global__ __launch_bounds__(256) void k_gemm(const float* __restrict__ A,
                                              const uint4* __restrict__ wb,
                                              const float* __restrict__ dis,
                                              uint* __restrict__ xwh) {
    __shared__ uint4 wlds[2048];                     // 32 KB fragment-major W
    int t = threadIdx.x;
    for (int i = t; i < 2048; i += 256) wlds[i] = wb[i];
    __syncthreads();

    int wave = t >> 6, lane = t & 63;
    int kg = lane >> 4;                              // k-group 0..3
    int row = blockIdx.x * 64 + wave * 16 + (lane & 15);
    int rowc = row < NN ? row : NN - 1;              // clamp for tail loads

    const float4* A4 = (const float4*)A;
    short8 afrag[4];
    #pragma unroll
    for (int kt = 0; kt < 4; kt++) {
        float4 pq0 = A4[(size_t)rowc * 32 + kt * 8 + kg * 2 + 0];
        float4 pq1 = A4[(size_t)rowc * 32 + kt * 8 + kg * 2 + 1];
        uint u0 = f2bf_pack(pq0.x, pq0.y);
        uint u1 = f2bf_pack(pq0.z, pq0.w);
        uint u2 = f2bf_pack(pq1.x, pq1.y);
        uint u3 = f2bf_pack(pq1.z, pq1.w);
        short8 f;
        f[0] = (short)(u0 & 0xffff); f[1] = (short)(u0 >> 16);
        f[2] = (short)(u1 & 0xffff); f[3] = (short)(u1 >> 16);
        f[4] = (short)(u2 & 0xffff); f[5] = (short)(u2 >> 16);
        f[6] = (short)(u3 & 0xffff); f[7] = (short)(u3 >> 16);
        afrag[kt] = f;
    }

    f32x4 acc[8];
    #pragma unroll
    for (int nt = 0; nt < 8; nt++) acc[nt] = (f32x4){0.f, 0.f, 0.f, 0.f};

    #pragma unroll
    for (int nt = 0; nt < 8; nt++) {
        #pragma unroll
        for (int kt = 0; kt < 4; kt++) {
            short8 bfrag = *(const short8*)&wlds[(nt * 4 + kt) * 64 + lane];
            acc[nt] = __builtin_amdgcn_mfma_f32_16x16x32_bf16(afrag[kt], bfrag, acc[nt], 0, 0, 0);
        }
    }

    // C/D layout: col = lane&15, row = (lane>>4)*4 + r ; scale row by dis[rout]
    float dv[4];
    #pragma unroll
    for (int r = 0; r < 4; r++) {
        int rout = blockIdx.x * 64 + wave * 16 + kg * 4 + r;
        dv[r] = (rout < NN) ? dis[rout] : 0.f;
    }
    ushort* xs = (ushort*)xwh;
    int col0 = lane & 15;
    #pragma unroll
    for (int nt = 0; nt < 8; nt++) {
        #pragma unroll
        for (int r = 0; r < 4; r++) {
            int rout = blockIdx.x * 64 + wave * 16 + kg * 4 + r;
            if (rout < NN)
                xs[(size_t)rout * FF + nt * 16 + col0] = (ushort)f2bf1(acc[nt][r] * dv[r]);
        }
    }
}

// ---- aggregate: one wave per node; h[d] = b + dis[d]*(xws[d] + sum ew*xws[s]) ----
__global__ __launch_bounds__(256) void k_agg(const int* __restrict__ indeg,
                                             const int2* __restrict__ eslot,
                                             const uint* __restrict__ xwh,
                                             const float* __restrict__ dis,
                                             const float* __restrict__ bias,
                                             uint* __restrict__ h32) {
    int wid = (blockIdx.x * blockDim.x + threadIdx.x) >> 6;
    int lane = threadIdx.x & 63;
    if (wid >= NN) return;
    int cnt = indeg[wid];
    float dd = dis[wid];
    uint us = xwh[(size_t)wid * 64 + lane];
    float px = bflo(us), py = bfhi(us);              // self term (weight 1)
    const int2* base = eslot + (size_t)wid * SLOT;
    int i = 0;
    for (; i + 3 < cnt; i += 4) {
        int2 p0 = base[i + 0];
        int2 p1 = base[i + 1];
        int2 p2 = base[i + 2];
        int2 p3 = base[i + 3];
        uint u0 = xwh[(size_t)p0.x * 64 + lane];
        uint u1 = xwh[(size_t)p1.x * 64 + lane];
        uint u2 = xwh[(size_t)p2.x * 64 + lane];
        uint u3 = xwh[(size_t)p3.x * 64 + lane];
        float w0 = __int_as_float(p0.y), w1 = __int_as_float(p1.y);
        float w2 = __int_as_float(p2.y), w3 = __int_as_float(p3.y);
        px += w0 * bflo(u0); py += w0 * bfhi(u0);
        px += w1 * bflo(u1); py += w1 * bfhi(u1);
        px += w2 * bflo(u2); py += w2 * bfhi(u2);
        px += w3 * bflo(u3); py += w3 * bfhi(u3);
    }
    for (; i < cnt; i++) {
        int2 p0 = base[i];
        uint u0 = xwh[(size_t)p0.x * 64 + lane];
        float w0 = __int_as_float(p0.y);
        px += w0 * bflo(u0); py += w0 * bfhi(u0);
    }
    float2 bb = ((const float2*)bias)[lane];
    h32[(size_t)wid * 64 + lane] = f2bf_pack(bb.x + dd * px, bb.y + dd * py);
}

// ---------------- per-graph sum/sumsq: (graph x 8 strips) blocks, atomic partials ----------------
__global__ __launch_bounds__(256) void k_gsums(const uint* __restrict__ h32,
                                               const int* __restrict__ gstart,
                                               float* __restrict__ sum1,
                                               float* __restrict__ sum2) {
    __shared__ float s1a[256], s1b[256], s2a[256], s2b[256];
    int g = blockIdx.x >> 3;
    int s = blockIdx.x & 7;
    int t = threadIdx.x;
    int f2 = t & 63;        // u32 (feature pair) index
    int half = t >> 6;      // 0..3
    int a = gstart[g], b = gstart[g + 1];
    float x0 = 0.f, x1 = 0.f, y0 = 0.f, y1 = 0.f;
    for (int n = a + s * 4 + half; n < b; n += 32) {
        uint u = h32[(size_t)n * 64 + f2];
        float v0 = bflo(u), v1 = bfhi(u);
        x0 += v0; x1 += v1; y0 += v0 * v0; y1 += v1 * v1;
    }
    s1a[t] = x0; s1b[t] = x1; s2a[t] = y0; s2b[t] = y1;
    __syncthreads();
    if (half == 0) {
        for (int j = 1; j < 4; j++) {
            x0 += s1a[t + j * 64]; x1 += s1b[t + j * 64];
            y0 += s2a[t + j * 64]; y1 += s2b[t + j * 64];
        }
        atomicAdd(&sum1[g * FF + f2 * 2 + 0], x0);
        atomicAdd(&sum1[g * FF + f2 * 2 + 1], x1);
        atomicAdd(&sum2[g * FF + f2 * 2 + 0], y0);
        atomicAdd(&sum2[g * FF + f2 * 2 + 1], y1);
    }
}

// ---------------- per (g,f): center c = mean*mean_scale, inv std ----------------
__global__ void k_gstats(const float* sum1, const float* sum2, const int* gstart,
                         const float* ms, float* cfac, float* istd) {
    int i = blockIdx.x * blockDim.x + threadIdx.x;
    if (i >= NG * FF) return;
    int g = i >> 7, f = i & 127;
    float cnt = (float)max(gstart[g + 1] - gstart[g], 1);
    float mean = sum1[i] / cnt;
    float c = mean * ms[f];
    float var = sum2[i] / cnt - 2.f * c * mean + c * c;  // E[(h-c)^2]
    var = fmaxf(var, 0.f);
    cfac[i] = c;
    istd[i] = rsqrtf(var + GN_EPS);
}

// ---------------- normalize + relu -> h_emb, fused per-graph max (atomicMax) ----------------
__global__ __launch_bounds__(256) void k_final(const uint* __restrict__ h32,
                                               const int* __restrict__ batch,
                                               const float* __restrict__ cfac,
                                               const float* __restrict__ istd,
                                               const float* __restrict__ gw,
                                               const float* __restrict__ gb,
                                               float* __restrict__ out,
                                               int* __restrict__ flat_i) {
    __shared__ float sm[8][FF];
    __shared__ int gg[8];
    int t = threadIdx.x;
    int n0 = blockIdx.x * 8;
    int rq = t >> 5;          // row within block (0..7)
    int q = t & 31;           // feature quad index
    int n = n0 + rq;
    if (t < 8) gg[t] = batch[n0 + t];
    int g = batch[n];
    int fq = q * 4;
    uint2 hu = *(const uint2*)&h32[(size_t)n * 64 + q * 2];
    float4 h4 = { bflo(hu.x), bfhi(hu.x), bflo(hu.y), bfhi(hu.y) };
    float4 c4 = *(const float4*)&cfac[g * FF + fq];
    float4 s4 = *(const float4*)&istd[g * FF + fq];
    float4 w4 = *(const float4*)&gw[fq];
    float4 b4 = *(const float4*)&gb[fq];
    float4 y;
    y.x = fmaxf(w4.x * (h4.x - c4.x) * s4.x + b4.x, 0.f);
    y.y = fmaxf(w4.y * (h4.y - c4.y) * s4.y + b4.y, 0.f);
    y.z = fmaxf(w4.z * (h4.z - c4.z) * s4.z + b4.z, 0.f);
    y.w = fmaxf(w4.w * (h4.w - c4.w) * s4.w + b4.w, 0.f);
    *(float4*)&out[(size_t)n * FF + fq] = y;
    *(float4*)&sm[rq][fq] = y;
    __syncthreads();
    if (t < FF) {
        int f = t;
        int gprev = gg[0];
        float m = 0.f;
        for (int r = 0; r < 8; r++) {
            int gr = gg[r];
            if (gr != gprev) {
                atomicMax(&flat_i[gprev * FF + f], __float_as_int(m));
                m = 0.f; gprev = gr;
            }
            m = fmaxf(m, sm[r][f]);
        }
        atomicMax(&flat_i[gprev * FF + f], __float_as_int(m));
    }
}

// ---------------- passthrough outputs (vectorized) ----------------
__global__ void k_copy(const int4* __restrict__ ei4, const float4* __restrict__ ew4,
                       const int4* __restrict__ b4, float* __restrict__ out_tail) {
    int i = blockIdx.x * blockDim.x + threadIdx.x;
    if (i < 2 * NE / 4) {
        int4 v = ei4[i];
        float4 o = { (float)v.x, (float)v.y, (float)v.z, (float)v.w };
        *(float4*)&out_tail[(size_t)i * 4] = o;
    } else if (i < 2 * NE / 4 + NE / 4) {
        int j = i - 2 * NE / 4;
        *(float4*)&out_tail[2 * NE + (size_t)j * 4] = ew4[j];
    } else if (i < 2 * NE / 4 + NE / 4 + NN / 4) {
        int j = i - (2 * NE / 4 + NE / 4);
        int4 v = b4[j];
        float4 o = { (float)v.x, (float)v.y, (float)v.z, (float)v.w };
        *(float4*)&out_tail[3 * NE + (size_t)j * 4] = o;
    }
}

extern "C" void kernel_launch(void* const* d_in, const int* in_sizes, int n_in,
                              void* d_out, int out_size, void* d_ws, size_t ws_size,
                              hipStream_t stream) {
    const float* inputs = (const float*)d_in[0];
    const int*   ei     = (const int*)d_in[1];
    const int*   batch  = (const int*)d_in[2];
    const float* ew     = (const float*)d_in[3];
    const float* W      = (const float*)d_in[4];
    const float* bias   = (const float*)d_in[5];
    const float* gnw    = (const float*)d_in[6];
    const float* gnb    = (const float*)d_in[7];
    const float* ms     = (const float*)d_in[8];
    float* out = (float*)d_out;

    // workspace layout
    char* p = (char*)d_ws;
    uint* xwh    = (uint*)p;  p += (size_t)NN * 64 * 4;       // bf16 xws (dis-scaled)
    uint* h32    = (uint*)p;  p += (size_t)NN * 64 * 4;       // bf16 h
    int2* eslot  = (int2*)p;  p += (size_t)NN * SLOT * 8;     // slotted edges
    ull* pk      = (ull*)p;   p += (size_t)NN * 8;            // packed deg/count
    float* dis   = (float*)p; p += (size_t)NN * 4;
    float* sum1  = (float*)p; p += (size_t)NG * FF * 4;
    float* sum2  = (float*)p; p += (size_t)NG * FF * 4;
    float* cfac  = (float*)p; p += (size_t)NG * FF * 4;
    float* istd  = (float*)p; p += (size_t)NG * FF * 4;
    int* indeg   = (int*)p;   p += (size_t)NN * 4;
    int* gstart  = (int*)p;   p += (size_t)(NG + 1) * 4;
    uint4* wb    = (uint4*)p; p += 2048 * 16;                 // fragment-major bf16 W

    const int TB = 256;
    int nblkN  = (NN + TB - 1) / TB;          // 391
    int nblkE  = (NE + TB - 1) / TB;          // 6250

    // output section offsets
    float* out_hemb = out;
    float* out_flat = out + (size_t)NN * FF;
    float* out_tail = out_flat + (size_t)NG * FF;
    int*   flat_i   = (int*)out_flat;

    k_init<<<nblkN, TB, 0, stream>>>(pk, sum1, sum2, flat_i);
    k_deg<<<nblkE, TB, 0, stream>>>(ei, ew, pk, eslot);
    k_dis<<<nblkN, TB, 0, stream>>>(pk, dis, indeg, batch, gstart);
    k_wcvt<<<8, 256, 0, stream>>>(W, wb);
    k_gemm<<<(NN + 63) / 64, 256, 0, stream>>>(inputs, wb, dis, xwh);
    k_agg<<<NN / 4, 256, 0, stream>>>(indeg, eslot, xwh, dis, bias, h32);
    k_gsums<<<NG * 8, 256, 0, stream>>>(h32, gstart, sum1, sum2);
    k_gstats<<<(NG * FF + TB - 1) / TB, TB, 0, stream>>>(sum1, sum2, gstart, ms, cfac, istd);
    k_final<<<NN / 8, 256, 0, stream>>>(h32, batch, cfac, istd, gnw, gnb, out_hemb, flat_i);
    k_copy<<<(2 * NE / 4 + NE / 4 + NN / 4 + TB - 1) / TB, TB, 0, stream>>>(
        (const int4*)ei, (const float4*)ew, (const int4*)batch, out_tail);
}